// Round 5
// baseline (25.610 us; speedup 1.0000x reference)
//
#include <hip/hip_runtime.h>

#define MAXLEN 4096
#define NB 16
#define NT 512     // tokens per batch == threads per block
#define ND 384
#define ND4 96     // D/4 float4 per frame

#define FCHUNK 128                         // frames per block
#define NCHUNK (MAXLEN / FCHUNK)           // 32 chunks per batch
#define ELEMS (FCHUNK * ND4)               // 12288 float4 per block
#define GITER (ELEMS / NT)                 // 24 gather iterations per thread

typedef float f32x4 __attribute__((ext_vector_type(4)));  // native vec for nt-store

// Fused length-regulator. Per block: redundant lightweight scan of its
// batch's 512 durations (wave-shuffle scan, 1 barrier), scatter token ids
// for its 128-frame chunk into LDS (interval ownership, no search), then
// stream the chunk with coalesced 16B gather + nontemporal store.
__global__ __launch_bounds__(NT) void lr_fused_kernel(
    const float* __restrict__ dur, const f32x4* __restrict__ enc,
    f32x4* __restrict__ out, float* __restrict__ len_out) {
  __shared__ int swave[8];        // per-wave scan totals
  __shared__ int sidx[FCHUNK];    // frame -> token index (-1 = zero)

  const int b = blockIdx.y;
  const int f0 = blockIdx.x * FCHUNK;
  const int t = threadIdx.x;
  const int lane = t & 63;
  const int w = t >> 6;           // wave id 0..7

  int n = (int)rintf(dur[b * NT + t]);  // RTE == jnp.round half-to-even
  if (n < 1) n = 1;

  // in-register inclusive scan across the wave (64 lanes, 6 steps)
  int v = n;
#pragma unroll
  for (int off = 1; off < 64; off <<= 1) {
    int u = __shfl_up(v, off, 64);
    if (lane >= off) v += u;
  }
  if (lane == 63) swave[w] = v;
  __syncthreads();                // barrier 1 of 2

  // per-thread: wave offset + block total from the 8 broadcast values
  int woff = 0, tot = 0;
#pragma unroll
  for (int i = 0; i < 8; ++i) {
    int sv = swave[i];
    tot += sv;
    if (i < w) woff += sv;
  }
  const int end = v + woff;       // inclusive cumsum for this token
  const int start = end - n;
  const int len = tot;

  // -1 fill for frames >= len in this chunk (disjoint from scatter below,
  // since scatter intervals exactly partition [0, len))
  if (t < FCHUNK && f0 + t >= len) sidx[t] = -1;
  // scatter: this thread's frames [start,end) ∩ [f0, f0+FCHUNK)
  {
    int lo = start > f0 ? start : f0;
    int hi = end < f0 + FCHUNK ? end : f0 + FCHUNK;
    for (int j = lo; j < hi; ++j) sidx[j - f0] = t;
  }
  if (blockIdx.x == 0 && t == 0) len_out[b] = (float)len;
  __syncthreads();                // barrier 2 of 2

  // streaming gather/store for this chunk
  const f32x4* encb = enc + (size_t)b * NT * ND4;
  f32x4* outb = out + ((size_t)b * MAXLEN + f0) * ND4;
#pragma unroll
  for (int k = 0; k < GITER; ++k) {
    const int j = t + k * NT;           // 0..12287
    const int lf = j / ND4;
    const int d4 = j - lf * ND4;
    const int idx = sidx[lf];
    const f32x4 z = {0.f, 0.f, 0.f, 0.f};
    f32x4 val = (idx >= 0) ? encb[idx * ND4 + d4] : z;
    __builtin_nontemporal_store(val, &outb[j]);
  }
}

extern "C" void kernel_launch(void* const* d_in, const int* in_sizes, int n_in,
                              void* d_out, int out_size, void* d_ws, size_t ws_size,
                              hipStream_t stream) {
  const float* enc = (const float*)d_in[0];   // [16,512,384] f32
  const float* dur = (const float*)d_in[1];   // [16,512] f32
  float* out_f = (float*)d_out;               // [16*4096*384] + [16]
  float* len_out = out_f + (size_t)NB * MAXLEN * ND;

  dim3 grid(NCHUNK, NB);
  lr_fused_kernel<<<grid, NT, 0, stream>>>(
      dur, (const f32x4*)enc, (f32x4*)d_out, len_out);
}

// Round 6
// 21.966 us; speedup vs baseline: 1.1659x; 1.1659x over previous
//
#include <hip/hip_runtime.h>

#define MAXLEN 4096
#define NB 16
#define NT 512     // tokens per batch == threads per block
#define ND 384
#define ND4 96     // D/4 float4 per frame

#define FCHUNK 128                         // frames per block
#define NCHUNK (MAXLEN / FCHUNK)           // 32 chunks per batch
#define ELEMS (FCHUNK * ND4)               // 12288 float4 per block
#define GITER (ELEMS / NT)                 // 24 gather iterations per thread
#define NXCD 8

typedef float f32x4 __attribute__((ext_vector_type(4)));

// Fused length-regulator. 1D grid of 512 blocks, XCD-pinned: blocks with
// bid%8==x serve batches {2x, 2x+1}, so each XCD's L2 holds only 1.57 MB of
// enc. Per block: wave-shuffle scan of the batch's 512 durations (2 barriers),
// LDS interval-scatter of token ids for a 128-frame chunk, then coalesced
// 16B gather + plain store (L2 write-combining — nt store measured -12%).
__global__ __launch_bounds__(NT) void lr_fused_kernel(
    const float* __restrict__ dur, const f32x4* __restrict__ enc,
    f32x4* __restrict__ out, float* __restrict__ len_out) {
  __shared__ int swave[8];        // per-wave scan totals
  __shared__ int sidx[FCHUNK];    // frame -> token index (-1 = zero)

  // XCD-pinned decomposition (dispatch round-robins bid across 8 XCDs)
  const int bid = blockIdx.x;
  const int xcd = bid & (NXCD - 1);
  const int slot = bid >> 3;            // 0..63
  const int b = 2 * xcd + (slot >> 5);  // 2 batches per XCD
  const int f0 = (slot & 31) * FCHUNK;  // chunk within batch

  const int t = threadIdx.x;
  const int lane = t & 63;
  const int w = t >> 6;           // wave id 0..7

  int n = (int)rintf(dur[b * NT + t]);  // RTE == jnp.round half-to-even
  if (n < 1) n = 1;

  // in-register inclusive scan across the wave (64 lanes, 6 steps)
  int v = n;
#pragma unroll
  for (int off = 1; off < 64; off <<= 1) {
    int u = __shfl_up(v, off, 64);
    if (lane >= off) v += u;
  }
  if (lane == 63) swave[w] = v;
  __syncthreads();                // barrier 1 of 2

  // per-thread: wave offset + block total from the 8 broadcast values
  int woff = 0, tot = 0;
#pragma unroll
  for (int i = 0; i < 8; ++i) {
    int sv = swave[i];
    tot += sv;
    if (i < w) woff += sv;
  }
  const int end = v + woff;       // inclusive cumsum for this token
  const int start = end - n;
  const int len = tot;

  // -1 fill for frames >= len in this chunk (disjoint from scatter below,
  // since scatter intervals exactly partition [0, len))
  if (t < FCHUNK && f0 + t >= len) sidx[t] = -1;
  // scatter: this thread's frames [start,end) ∩ [f0, f0+FCHUNK)
  {
    int lo = start > f0 ? start : f0;
    int hi = end < f0 + FCHUNK ? end : f0 + FCHUNK;
    for (int j = lo; j < hi; ++j) sidx[j - f0] = t;
  }
  if (f0 == 0 && t == 0) len_out[b] = (float)len;
  __syncthreads();                // barrier 2 of 2

  // streaming gather/store for this chunk
  const f32x4* encb = enc + (size_t)b * NT * ND4;
  f32x4* outb = out + ((size_t)b * MAXLEN + f0) * ND4;
#pragma unroll
  for (int k = 0; k < GITER; ++k) {
    const int j = t + k * NT;           // 0..12287
    const int lf = j / ND4;
    const int d4 = j - lf * ND4;
    const int idx = sidx[lf];
    const f32x4 z = {0.f, 0.f, 0.f, 0.f};
    f32x4 val = (idx >= 0) ? encb[idx * ND4 + d4] : z;
    outb[j] = val;
  }
}

extern "C" void kernel_launch(void* const* d_in, const int* in_sizes, int n_in,
                              void* d_out, int out_size, void* d_ws, size_t ws_size,
                              hipStream_t stream) {
  const float* enc = (const float*)d_in[0];   // [16,512,384] f32
  const float* dur = (const float*)d_in[1];   // [16,512] f32
  float* out_f = (float*)d_out;               // [16*4096*384] + [16]
  float* len_out = out_f + (size_t)NB * MAXLEN * ND;

  lr_fused_kernel<<<NB * NCHUNK, NT, 0, stream>>>(
      dur, (const f32x4*)enc, (f32x4*)d_out, len_out);
}

// Round 7
// 21.856 us; speedup vs baseline: 1.1718x; 1.0050x over previous
//
#include <hip/hip_runtime.h>

#define MAXLEN 4096
#define NB 16
#define NT 512     // tokens per batch == threads per block
#define ND 384
#define ND4 96     // D/4 float4 per frame

#define FCHUNK 128                         // frames per block
#define NCHUNK (MAXLEN / FCHUNK)           // 32 chunks per batch
#define ELEMS (FCHUNK * ND4)               // 12288 float4 per block
#define GITER (ELEMS / NT)                 // 24 gather iterations per thread
#define NXCD 8

typedef float f32x4 __attribute__((ext_vector_type(4)));

// Fused length-regulator. 1D grid of 512 blocks, XCD-pinned: blocks with
// bid%8==x serve batches {2x, 2x+1} (1.57 MB of enc per XCD-L2). Per block:
// wave-shuffle scan of the batch's 512 durations (2 barriers), LDS
// interval-scatter of token ids for a 128-frame chunk, then a split
// streaming loop: pure gather+store for the data region, one mixed boundary
// iteration, pure store-only (fill-style) for the zero region.
__global__ __launch_bounds__(NT) void lr_fused_kernel(
    const float* __restrict__ dur, const f32x4* __restrict__ enc,
    f32x4* __restrict__ out, float* __restrict__ len_out) {
  __shared__ int swave[8];        // per-wave scan totals
  __shared__ int sidx[FCHUNK];    // frame -> token index (-1 = zero)

  // XCD-pinned decomposition (dispatch round-robins bid across 8 XCDs)
  const int bid = blockIdx.x;
  const int xcd = bid & (NXCD - 1);
  const int slot = bid >> 3;            // 0..63
  const int b = 2 * xcd + (slot >> 5);  // 2 batches per XCD
  const int f0 = (slot & 31) * FCHUNK;  // chunk within batch

  const int t = threadIdx.x;
  const int lane = t & 63;
  const int w = t >> 6;           // wave id 0..7

  int n = (int)rintf(dur[b * NT + t]);  // RTE == jnp.round half-to-even
  if (n < 1) n = 1;

  // in-register inclusive scan across the wave (64 lanes, 6 steps)
  int v = n;
#pragma unroll
  for (int off = 1; off < 64; off <<= 1) {
    int u = __shfl_up(v, off, 64);
    if (lane >= off) v += u;
  }
  if (lane == 63) swave[w] = v;
  __syncthreads();                // barrier 1 of 2

  // per-thread: wave offset + block total from the 8 broadcast values
  int woff = 0, tot = 0;
#pragma unroll
  for (int i = 0; i < 8; ++i) {
    int sv = swave[i];
    tot += sv;
    if (i < w) woff += sv;
  }
  const int end = v + woff;       // inclusive cumsum for this token
  const int start = end - n;
  const int len = tot;

  // -1 fill for frames >= len in this chunk (disjoint from scatter below,
  // since scatter intervals exactly partition [0, len))
  if (t < FCHUNK && f0 + t >= len) sidx[t] = -1;
  // scatter: this thread's frames [start,end) ∩ [f0, f0+FCHUNK)
  {
    int lo = start > f0 ? start : f0;
    int hi = end < f0 + FCHUNK ? end : f0 + FCHUNK;
    for (int j = lo; j < hi; ++j) sidx[j - f0] = t;
  }
  if (f0 == 0 && t == 0) len_out[b] = (float)len;
  __syncthreads();                // barrier 2 of 2

  // data/zero split for this chunk: frames [0, dlim) are data, rest zero
  int dlim = len - f0;
  if (dlim < 0) dlim = 0;
  if (dlim > FCHUNK) dlim = FCHUNK;
  const int jlim = dlim * ND4;    // element bound of data region

  const f32x4* encb = enc + (size_t)b * NT * ND4;
  f32x4* outb = out + ((size_t)b * MAXLEN + f0) * ND4;
  const f32x4 z = {0.f, 0.f, 0.f, 0.f};

  int k = 0;
  // pure-data iterations: whole 512-element slab below jlim
#pragma unroll 4
  for (; (k + 1) * NT <= jlim; ++k) {
    const int j = t + k * NT;
    const int lf = j / ND4;
    const int d4 = j - lf * ND4;
    outb[j] = encb[sidx[lf] * ND4 + d4];
  }
  // one mixed boundary iteration (if any)
  if (k * NT < jlim) {
    const int j = t + k * NT;
    const int lf = j / ND4;
    const int d4 = j - lf * ND4;
    const int idx = sidx[lf];
    f32x4 val = (idx >= 0) ? encb[idx * ND4 + d4] : z;
    outb[j] = val;
    ++k;
  }
  // pure-zero iterations: store-only, fill-kernel style
#pragma unroll 4
  for (; k < GITER; ++k) {
    outb[t + k * NT] = z;
  }
}

extern "C" void kernel_launch(void* const* d_in, const int* in_sizes, int n_in,
                              void* d_out, int out_size, void* d_ws, size_t ws_size,
                              hipStream_t stream) {
  const float* enc = (const float*)d_in[0];   // [16,512,384] f32
  const float* dur = (const float*)d_in[1];   // [16,512] f32
  float* out_f = (float*)d_out;               // [16*4096*384] + [16]
  float* len_out = out_f + (size_t)NB * MAXLEN * ND;

  lr_fused_kernel<<<NB * NCHUNK, NT, 0, stream>>>(
      dur, (const f32x4*)enc, (f32x4*)d_out, len_out);
}